// Round 9
// baseline (241.578 us; speedup 1.0000x reference)
//
#include <hip/hip_runtime.h>
#include <hip/hip_bf16.h>

// B=2048, N=64, C=256, F=256
// out[b,n,f] = d[f,n]*h0[b,n,f] + sum_m off[f,n,m]*h1[b,m,f] + bias[f]
// v9: k_eout rewritten LDS-free: wave owns an n-slice and loops ALL 16 f;
// lane's (n,b) is constant across fi -> f-values accumulate in registers,
// no LDS exchange, no barrier. k_pre/k_gemm identical to v8.

typedef __attribute__((ext_vector_type(8))) short  fragA;   // 8 bf16 = 4 VGPR
typedef __attribute__((ext_vector_type(4))) float  f32x4;
typedef __attribute__((ext_vector_type(8))) unsigned short u16x8;
typedef __attribute__((ext_vector_type(4))) unsigned short u16x4;

// workspace layout (bytes)
constexpr long OFF_OFF = 0;                          // bf16 off [256][64][64] (2 MB)
constexpr long OFF_WT  = 2l * 1024 * 1024;           // bf16 Wt flat [512][256] (256 KB)
constexpr long OFF_DS  = OFF_WT + 512l * 256 * 2;    // f32 dscale [64][256]   (64 KB)
constexpr long OFF_XB  = OFF_DS + 64l * 256 * 4;     // bf16 xb  [131072][256] (67 MB)
constexpr long OFF_G0  = OFF_XB + 131072l * 256 * 2; // bf16 g0  [131072][256] (67 MB)
constexpr long OFF_H1T = OFF_G0 + 131072l * 256 * 2; // bf16 h1t [256][131072] (67 MB)
constexpr long WS_NEED = OFF_H1T + 131072l * 256 * 2;

static __device__ inline unsigned short f2bf(float f) {
  __hip_bfloat16 h = __float2bfloat16(f);
  return __builtin_bit_cast(unsigned short, h);
}
static __device__ inline float bf2f(unsigned short u) {
  unsigned int x = ((unsigned int)u) << 16;
  return __builtin_bit_cast(float, x);
}
static __device__ inline unsigned int packbf(float a, float b) {
  return (unsigned int)f2bf(a) | ((unsigned int)f2bf(b) << 16);
}
static __device__ __forceinline__ void gl16(const void* g, void* l) {
  __builtin_amdgcn_global_load_lds(
      (const __attribute__((address_space(1))) unsigned int*)g,
      (__attribute__((address_space(3))) unsigned int*)l, 16, 0, 0);
}
static __device__ __forceinline__ f32x4 mfma16(fragA a, fragA b, f32x4 c) {
  return __builtin_amdgcn_mfma_f32_16x16x32_bf16(a, b, c, 0, 0, 0);
}

// ---------------------------------------------------------------- k_pre
// blocks 0..4095: softmax prep; 4096..6143: x->bf16; 6144..6175: W->Wt
__global__ __launch_bounds__(256) void k_pre(const float* __restrict__ x,
                                             const float* __restrict__ e,
                                             const float* __restrict__ W,
                                             const unsigned char* __restrict__ mask,
                                             char* __restrict__ ws_b) {
  const int bid = blockIdx.x;
  const int tid = threadIdx.x;
  if (bid < 4096) {
    unsigned short* off = (unsigned short*)(ws_b + OFF_OFF);
    float* dscale = (float*)(ws_b + OFF_DS);
    const int lane = tid & 63;
    const int row  = bid * 4 + (tid >> 6);   // f*64 + n
    const int n = row & 63;
    bool is_u8 = __all(mask[lane * 65] != 0);  // diag guaranteed true
    bool mv;
    if (is_u8) mv = mask[n * 64 + lane] != 0;
    else       mv = ((const int*)mask)[n * 64 + lane] != 0;
    float v = mv ? e[(long)row * 64 + lane] : -1e30f;
    float mx = v;
#pragma unroll
    for (int s = 32; s; s >>= 1) mx = fmaxf(mx, __shfl_xor(mx, s));
    float ex = mv ? __expf(v - mx) : 0.f;
    float sm = ex;
#pragma unroll
    for (int s = 32; s; s >>= 1) sm += __shfl_xor(sm, s);
    float adj = ex / sm;
    const int f = row >> 6;
    if (lane == n) dscale[n * 256 + f] = adj;
    off[(long)row * 64 + lane] = f2bf(lane == n ? 0.f : adj);
  } else if (bid < 6144) {
    unsigned short* xb = (unsigned short*)(ws_b + OFF_XB);
    long i = ((long)(bid - 4096) * 256 + tid) * 8;
    const long stride = 2048l * 256 * 8;
    const long total = 131072l * 256;
    for (; i < total; i += stride) {
      float4 a = *(const float4*)(x + i);
      float4 b = *(const float4*)(x + i + 4);
      u16x8 p;
      p[0] = f2bf(a.x); p[1] = f2bf(a.y); p[2] = f2bf(a.z); p[3] = f2bf(a.w);
      p[4] = f2bf(b.x); p[5] = f2bf(b.y); p[6] = f2bf(b.z); p[7] = f2bf(b.w);
      *(u16x8*)(xb + i) = p;
    }
  } else {
    unsigned short* Wt = (unsigned short*)(ws_b + OFF_WT);
    __shared__ float t[64][65];
    const int b2 = bid - 6144;          // 32 blocks: w(2) x f0(4) x c0(4)
    const int w = b2 >> 4, f0 = ((b2 >> 2) & 3) * 64, c0 = (b2 & 3) * 64;
    const int tr = tid >> 2, tc = (tid & 3) * 16;
    const float* src = W + ((long)(w * 256 + c0 + tr)) * 256 + f0 + tc;
#pragma unroll
    for (int i = 0; i < 16; i += 4) {
      float4 v = *(const float4*)(src + i);
      t[tr][tc + i] = v.x; t[tr][tc + i + 1] = v.y;
      t[tr][tc + i + 2] = v.z; t[tr][tc + i + 3] = v.w;
    }
    __syncthreads();
    u16x8 p0, p1;
#pragma unroll
    for (int i = 0; i < 8; i++)  p0[i] = f2bf(t[tc + i][tr]);
#pragma unroll
    for (int i = 0; i < 8; i++)  p1[i] = f2bf(t[tc + 8 + i][tr]);
    unsigned short* dst = Wt + ((long)(w * 256 + f0 + tr)) * 256 + c0 + tc;
    *(u16x8*)dst = p0;
    *(u16x8*)(dst + 8) = p1;
  }
}

// ---------------------------------------------------------------- k_gemm
// grid 8192, block 256 (4 waves), launch_bounds(256,5) -> 5 blocks/CU.
// Tile 128 rows x 64 cols (32 f x {h0,h1}), K=256 in 4 steps.
// SINGLE-buffered arena 24KB: A @0 [128 rows][128 B], B @16384 [64 cols][128 B].
__global__ __launch_bounds__(256, 5) void k_gemm(char* __restrict__ ws_b) {
  const float* dscale = (const float*)(ws_b + OFF_DS);
  const char* xb_b = ws_b + OFF_XB;
  const char* wt_b = ws_b + OFF_WT;
  unsigned short* g0g = (unsigned short*)(ws_b + OFF_G0);
  unsigned short* h1t = (unsigned short*)(ws_b + OFF_H1T);

  __shared__ __align__(16) char arena[24576];

  const int tid = threadIdx.x;
  const int wid = tid >> 6, lane = tid & 63;
  const int lr = lane & 15, qu = lane >> 4;

  const int wg = blockIdx.x;
  const int xcd = wg & 7, s = wg >> 3;           // s 0..1023
  const int rg = xcd * 128 + (s >> 3);           // 0..1023 row-groups of 128
  const int cg = s & 7;                          // col-group cycles fast (L2)
  const int f0 = cg * 32;
  const long R0 = (long)rg * 128;

  const int ar   = tid >> 3;                     // 0..31
  const int aswz = (((tid & 7) ^ (ar & 7)) << 4);
  const int wrow0 = f0 + ar;                     // B cols 0..31 (W0)
  const int wrow1 = 256 + f0 + ar;               // B cols 32..63 (W1)

  auto STAGE = [&](int ks) {
    const long ko = (long)ks * 128;
#pragma unroll
    for (int i = 0; i < 4; i++)
      gl16(xb_b + (R0 + i * 32 + ar) * 512 + ko + aswz,
           arena + i * 4096 + tid * 16);
    gl16(wt_b + (long)wrow0 * 512 + ko + aswz, arena + 16384 + tid * 16);
    gl16(wt_b + (long)wrow1 * 512 + ko + aswz, arena + 16384 + 4096 + tid * 16);
  };

  STAGE(0);
  f32x4 acc[2][4] = {};
  const int arow0 = wid * 32;

  for (int ks = 0; ks < 4; ks++) {
    __syncthreads();      // vmcnt drained -> tiles visible
#pragma unroll
    for (int kk = 0; kk < 2; kk++) {
      fragA af[2], bfr[4];
#pragma unroll
      for (int i2 = 0; i2 < 2; i2++) {
        int r = arow0 + i2 * 16 + lr;
        af[i2] = *(const fragA*)(arena + r * 128 +
                     ((kk * 64 + qu * 16) ^ ((lr & 7) << 4)));
      }
#pragma unroll
      for (int j = 0; j < 4; j++) {
        int cc = j * 16 + lr;
        bfr[j] = *(const fragA*)(arena + 16384 + cc * 128 +
                     ((kk * 64 + qu * 16) ^ ((lr & 7) << 4)));
      }
#pragma unroll
      for (int i2 = 0; i2 < 2; i2++)
#pragma unroll
        for (int j = 0; j < 4; j++)
          acc[i2][j] = mfma16(af[i2], bfr[j], acc[i2][j]);
    }
    __syncthreads();      // all waves done reading this tile
    if (ks < 3) STAGE(ks + 1);
  }

  // ---- epilogue staging: Gs [128][40] @0 (10240 B), Ts [32][136] @10240
  unsigned short* Gs = (unsigned short*)(arena);
  unsigned short* Ts = (unsigned short*)(arena + 10240);
#pragma unroll
  for (int i2 = 0; i2 < 2; i2++) {
#pragma unroll
    for (int j = 0; j < 2; j++) {      // h0 -> dscale*h0
      int f = f0 + j * 16 + lr;
#pragma unroll
      for (int r = 0; r < 4; r++) {
        int rloc = arow0 + i2 * 16 + qu * 4 + r;
        int n = rloc & 63;
        Gs[rloc * 40 + j * 16 + lr] = f2bf(dscale[n * 256 + f] * acc[i2][j][r]);
      }
    }
#pragma unroll
    for (int j = 2; j < 4; j++) {      // h1 -> Ts[fl][rloc]
      int fl = (j - 2) * 16 + lr;
      int rb = arow0 + i2 * 16 + qu * 4;
      u16x4 pk;
      pk[0] = f2bf(acc[i2][j][0]); pk[1] = f2bf(acc[i2][j][1]);
      pk[2] = f2bf(acc[i2][j][2]); pk[3] = f2bf(acc[i2][j][3]);
      *(u16x4*)(Ts + fl * 136 + rb) = pk;
    }
  }
  __syncthreads();

  {   // g0: 2 threads/row, 32B each
    int row = tid >> 1, half = tid & 1;
    const unsigned short* sp = Gs + row * 40 + half * 16;
    unsigned short* dp = g0g + (R0 + row) * 256 + f0 + half * 16;
    *(u16x8*)dp = *(const u16x8*)sp;
    *(u16x8*)(dp + 8) = *(const u16x8*)(sp + 8);
  }
  {   // h1t: 8 threads/f, 32B each
    int f = tid >> 3, seg = tid & 7;
    const unsigned short* sp = Ts + f * 136 + seg * 16;
    unsigned short* dp = h1t + (long)(f0 + f) * 131072 + R0 + seg * 16;
    *(u16x8*)dp = *(const u16x8*)sp;
    *(u16x8*)(dp + 8) = *(const u16x8*)(sp + 8);
  }
}

// ---------------------------------------------------------------- k_eout
// grid 2048, block 256 (4 waves), NO LDS, NO barrier.
// Block = 16 batches x 16 f; wave w owns n-rows [w*16, w*16+16) and loops
// ALL 16 f. Lane's output coords (n = nw+qu*4+j, b = lr) are constant
// across fi, so the 16 f-values accumulate in registers (bf16-packed).
__global__ __launch_bounds__(256, 5) void k_eout(const float* __restrict__ bias,
                                                 const char* __restrict__ ws_b,
                                                 float* __restrict__ out) {
  const unsigned short* offp = (const unsigned short*)(ws_b + OFF_OFF);
  const unsigned short* h1t  = (const unsigned short*)(ws_b + OFF_H1T);
  const unsigned short* g0g  = (const unsigned short*)(ws_b + OFF_G0);

  const int tid = threadIdx.x;
  const int wid = tid >> 6, lane = tid & 63;
  const int lr = lane & 15, qu = lane >> 4;

  const int wg = blockIdx.x;
  const int xcd = wg & 7, u = wg >> 3;           // u 0..255
  const int bg = xcd * 16 + (u >> 4);            // 0..127 (16-batch groups)
  const int fg = u & 15;                         // f-group cycles fast (L2)
  const long B0 = (long)bg * 16;
  const int f0 = fg * 16;
  const int nw = wid * 16;

  const unsigned short* obase = offp + (long)f0 * 4096 + (nw + lr) * 64 + qu * 8;
  const unsigned short* hbase = h1t + (long)f0 * 131072 + (B0 + lr) * 64 + qu * 8;

  unsigned int eb[4][8];   // [j][fi/2] packed bf16 pairs of eins

#pragma unroll
  for (int fp = 0; fp < 8; fp++) {
    const unsigned short* ob0 = obase + (long)(2 * fp) * 4096;
    const unsigned short* hb0 = hbase + (long)(2 * fp) * 131072;
    const unsigned short* ob1 = ob0 + 4096;
    const unsigned short* hb1 = hb0 + 131072;
    fragA oa0 = *(const fragA*)(ob0);
    fragA oa1 = *(const fragA*)(ob0 + 32);
    fragA ha0 = *(const fragA*)(hb0);
    fragA ha1 = *(const fragA*)(hb0 + 32);
    fragA oc0 = *(const fragA*)(ob1);
    fragA oc1 = *(const fragA*)(ob1 + 32);
    fragA hc0 = *(const fragA*)(hb1);
    fragA hc1 = *(const fragA*)(hb1 + 32);
    f32x4 e0 = {}, e1 = {};
    e0 = mfma16(oa0, ha0, e0);
    e1 = mfma16(oc0, hc0, e1);
    e0 = mfma16(oa1, ha1, e0);
    e1 = mfma16(oc1, hc1, e1);
#pragma unroll
    for (int j = 0; j < 4; j++)
      eb[j][fp] = packbf(e0[j], e1[j]);
  }

  // ---- epilogue: out = g0 + eins + bias (per lane: 4 rows x 16 f)
  float4 bv[4];
#pragma unroll
  for (int k = 0; k < 4; k++) bv[k] = ((const float4*)(bias + f0))[k];

#pragma unroll
  for (int j = 0; j < 4; j++) {
    long R = (B0 + lr) * 64 + nw + qu * 4 + j;
    const unsigned short* gp = g0g + R * 256 + f0;
    u16x8 gv0 = ((const u16x8*)gp)[0];
    u16x8 gv1 = ((const u16x8*)gp)[1];
    float4* op = (float4*)(out + R * 256 + f0);
#pragma unroll
    for (int k = 0; k < 4; k++) {
      unsigned int p0 = eb[j][k * 2], p1 = eb[j][k * 2 + 1];
      float g0e = bf2f(k < 2 ? gv0[k * 4 + 0] : gv1[(k - 2) * 4 + 0]);
      float g1e = bf2f(k < 2 ? gv0[k * 4 + 1] : gv1[(k - 2) * 4 + 1]);
      float g2e = bf2f(k < 2 ? gv0[k * 4 + 2] : gv1[(k - 2) * 4 + 2]);
      float g3e = bf2f(k < 2 ? gv0[k * 4 + 3] : gv1[(k - 2) * 4 + 3]);
      float4 ov;
      ov.x = g0e + bf2f((unsigned short)(p0 & 0xffff)) + bv[k].x;
      ov.y = g1e + bf2f((unsigned short)(p0 >> 16)) + bv[k].y;
      ov.z = g2e + bf2f((unsigned short)(p1 & 0xffff)) + bv[k].z;
      ov.w = g3e + bf2f((unsigned short)(p1 >> 16)) + bv[k].w;
      op[k] = ov;
    }
  }
}

// ---------------------------------------------------------------- launch
extern "C" void kernel_launch(void* const* d_in, const int* in_sizes, int n_in,
                              void* d_out, int out_size, void* d_ws, size_t ws_size,
                              hipStream_t stream) {
  const float* x    = (const float*)d_in[0];
  const float* W    = (const float*)d_in[1];
  const float* e    = (const float*)d_in[2];
  const float* bias = (const float*)d_in[3];
  const unsigned char* mask = (const unsigned char*)d_in[4];
  float* out = (float*)d_out;
  char* ws = (char*)d_ws;
  if (ws_size < (size_t)WS_NEED) return;

  k_pre<<<6176, 256, 0, stream>>>(x, e, W, mask, ws);
  k_gemm<<<8192, 256, 0, stream>>>(ws);
  k_eout<<<2048, 256, 0, stream>>>(bias, ws, out);
}

// Round 10
// 208.658 us; speedup vs baseline: 1.1578x; 1.1578x over previous
//
#include <hip/hip_runtime.h>
#include <hip/hip_bf16.h>

// B=2048, N=64, C=256, F=256
// out[b,n,f] = d[f,n]*h0[b,n,f] + sum_m off[f,n,m]*h1[b,m,f] + bias[f]
// v10: k_eout = GEMM-style einsum: gl16-staged h1t (32KB once) + per-f
// dbuf off tiles (2x8KB, 1 barrier/f-step), MFMA from LDS, f-results
// accumulate in registers (no LDS exchange), R9 coalesced epilogue.
// k_pre / k_gemm identical to v8.

typedef __attribute__((ext_vector_type(8))) short  fragA;   // 8 bf16 = 4 VGPR
typedef __attribute__((ext_vector_type(4))) float  f32x4;
typedef __attribute__((ext_vector_type(8))) unsigned short u16x8;
typedef __attribute__((ext_vector_type(4))) unsigned short u16x4;

// workspace layout (bytes)
constexpr long OFF_OFF = 0;                          // bf16 off [256][64][64] (2 MB)
constexpr long OFF_WT  = 2l * 1024 * 1024;           // bf16 Wt flat [512][256] (256 KB)
constexpr long OFF_DS  = OFF_WT + 512l * 256 * 2;    // f32 dscale [64][256]   (64 KB)
constexpr long OFF_XB  = OFF_DS + 64l * 256 * 4;     // bf16 xb  [131072][256] (67 MB)
constexpr long OFF_G0  = OFF_XB + 131072l * 256 * 2; // bf16 g0  [131072][256] (67 MB)
constexpr long OFF_H1T = OFF_G0 + 131072l * 256 * 2; // bf16 h1t [256][131072] (67 MB)
constexpr long WS_NEED = OFF_H1T + 131072l * 256 * 2;

static __device__ inline unsigned short f2bf(float f) {
  __hip_bfloat16 h = __float2bfloat16(f);
  return __builtin_bit_cast(unsigned short, h);
}
static __device__ inline float bf2f(unsigned short u) {
  unsigned int x = ((unsigned int)u) << 16;
  return __builtin_bit_cast(float, x);
}
static __device__ inline unsigned int packbf(float a, float b) {
  return (unsigned int)f2bf(a) | ((unsigned int)f2bf(b) << 16);
}
static __device__ __forceinline__ void gl16(const void* g, void* l) {
  __builtin_amdgcn_global_load_lds(
      (const __attribute__((address_space(1))) unsigned int*)g,
      (__attribute__((address_space(3))) unsigned int*)l, 16, 0, 0);
}
static __device__ __forceinline__ f32x4 mfma16(fragA a, fragA b, f32x4 c) {
  return __builtin_amdgcn_mfma_f32_16x16x32_bf16(a, b, c, 0, 0, 0);
}

// ---------------------------------------------------------------- k_pre
// blocks 0..4095: softmax prep; 4096..6143: x->bf16; 6144..6175: W->Wt
__global__ __launch_bounds__(256) void k_pre(const float* __restrict__ x,
                                             const float* __restrict__ e,
                                             const float* __restrict__ W,
                                             const unsigned char* __restrict__ mask,
                                             char* __restrict__ ws_b) {
  const int bid = blockIdx.x;
  const int tid = threadIdx.x;
  if (bid < 4096) {
    unsigned short* off = (unsigned short*)(ws_b + OFF_OFF);
    float* dscale = (float*)(ws_b + OFF_DS);
    const int lane = tid & 63;
    const int row  = bid * 4 + (tid >> 6);   // f*64 + n
    const int n = row & 63;
    bool is_u8 = __all(mask[lane * 65] != 0);  // diag guaranteed true
    bool mv;
    if (is_u8) mv = mask[n * 64 + lane] != 0;
    else       mv = ((const int*)mask)[n * 64 + lane] != 0;
    float v = mv ? e[(long)row * 64 + lane] : -1e30f;
    float mx = v;
#pragma unroll
    for (int s = 32; s; s >>= 1) mx = fmaxf(mx, __shfl_xor(mx, s));
    float ex = mv ? __expf(v - mx) : 0.f;
    float sm = ex;
#pragma unroll
    for (int s = 32; s; s >>= 1) sm += __shfl_xor(sm, s);
    float adj = ex / sm;
    const int f = row >> 6;
    if (lane == n) dscale[n * 256 + f] = adj;
    off[(long)row * 64 + lane] = f2bf(lane == n ? 0.f : adj);
  } else if (bid < 6144) {
    unsigned short* xb = (unsigned short*)(ws_b + OFF_XB);
    long i = ((long)(bid - 4096) * 256 + tid) * 8;
    const long stride = 2048l * 256 * 8;
    const long total = 131072l * 256;
    for (; i < total; i += stride) {
      float4 a = *(const float4*)(x + i);
      float4 b = *(const float4*)(x + i + 4);
      u16x8 p;
      p[0] = f2bf(a.x); p[1] = f2bf(a.y); p[2] = f2bf(a.z); p[3] = f2bf(a.w);
      p[4] = f2bf(b.x); p[5] = f2bf(b.y); p[6] = f2bf(b.z); p[7] = f2bf(b.w);
      *(u16x8*)(xb + i) = p;
    }
  } else {
    unsigned short* Wt = (unsigned short*)(ws_b + OFF_WT);
    __shared__ float t[64][65];
    const int b2 = bid - 6144;          // 32 blocks: w(2) x f0(4) x c0(4)
    const int w = b2 >> 4, f0 = ((b2 >> 2) & 3) * 64, c0 = (b2 & 3) * 64;
    const int tr = tid >> 2, tc = (tid & 3) * 16;
    const float* src = W + ((long)(w * 256 + c0 + tr)) * 256 + f0 + tc;
#pragma unroll
    for (int i = 0; i < 16; i += 4) {
      float4 v = *(const float4*)(src + i);
      t[tr][tc + i] = v.x; t[tr][tc + i + 1] = v.y;
      t[tr][tc + i + 2] = v.z; t[tr][tc + i + 3] = v.w;
    }
    __syncthreads();
    u16x8 p0, p1;
#pragma unroll
    for (int i = 0; i < 8; i++)  p0[i] = f2bf(t[tc + i][tr]);
#pragma unroll
    for (int i = 0; i < 8; i++)  p1[i] = f2bf(t[tc + 8 + i][tr]);
    unsigned short* dst = Wt + ((long)(w * 256 + f0 + tr)) * 256 + c0 + tc;
    *(u16x8*)dst = p0;
    *(u16x8*)(dst + 8) = p1;
  }
}

// ---------------------------------------------------------------- k_gemm
// grid 8192, block 256 (4 waves), launch_bounds(256,5) -> 5 blocks/CU.
// Tile 128 rows x 64 cols (32 f x {h0,h1}), K=256 in 4 steps.
// SINGLE-buffered arena 24KB: A @0 [128 rows][128 B], B @16384 [64 cols][128 B].
__global__ __launch_bounds__(256, 5) void k_gemm(char* __restrict__ ws_b) {
  const float* dscale = (const float*)(ws_b + OFF_DS);
  const char* xb_b = ws_b + OFF_XB;
  const char* wt_b = ws_b + OFF_WT;
  unsigned short* g0g = (unsigned short*)(ws_b + OFF_G0);
  unsigned short* h1t = (unsigned short*)(ws_b + OFF_H1T);

  __shared__ __align__(16) char arena[24576];

  const int tid = threadIdx.x;
  const int wid = tid >> 6, lane = tid & 63;
  const int lr = lane & 15, qu = lane >> 4;

  const int wg = blockIdx.x;
  const int xcd = wg & 7, s = wg >> 3;           // s 0..1023
  const int rg = xcd * 128 + (s >> 3);           // 0..1023 row-groups of 128
  const int cg = s & 7;                          // col-group cycles fast (L2)
  const int f0 = cg * 32;
  const long R0 = (long)rg * 128;

  const int ar   = tid >> 3;                     // 0..31
  const int aswz = (((tid & 7) ^ (ar & 7)) << 4);
  const int wrow0 = f0 + ar;                     // B cols 0..31 (W0)
  const int wrow1 = 256 + f0 + ar;               // B cols 32..63 (W1)

  auto STAGE = [&](int ks) {
    const long ko = (long)ks * 128;
#pragma unroll
    for (int i = 0; i < 4; i++)
      gl16(xb_b + (R0 + i * 32 + ar) * 512 + ko + aswz,
           arena + i * 4096 + tid * 16);
    gl16(wt_b + (long)wrow0 * 512 + ko + aswz, arena + 16384 + tid * 16);
    gl16(wt_b + (long)wrow1 * 512 + ko + aswz, arena + 16384 + 4096 + tid * 16);
  };

  STAGE(0);
  f32x4 acc[2][4] = {};
  const int arow0 = wid * 32;

  for (int ks = 0; ks < 4; ks++) {
    __syncthreads();      // vmcnt drained -> tiles visible
#pragma unroll
    for (int kk = 0; kk < 2; kk++) {
      fragA af[2], bfr[4];
#pragma unroll
      for (int i2 = 0; i2 < 2; i2++) {
        int r = arow0 + i2 * 16 + lr;
        af[i2] = *(const fragA*)(arena + r * 128 +
                     ((kk * 64 + qu * 16) ^ ((lr & 7) << 4)));
      }
#pragma unroll
      for (int j = 0; j < 4; j++) {
        int cc = j * 16 + lr;
        bfr[j] = *(const fragA*)(arena + 16384 + cc * 128 +
                     ((kk * 64 + qu * 16) ^ ((lr & 7) << 4)));
      }
#pragma unroll
      for (int i2 = 0; i2 < 2; i2++)
#pragma unroll
        for (int j = 0; j < 4; j++)
          acc[i2][j] = mfma16(af[i2], bfr[j], acc[i2][j]);
    }
    __syncthreads();      // all waves done reading this tile
    if (ks < 3) STAGE(ks + 1);
  }

  // ---- epilogue staging: Gs [128][40] @0 (10240 B), Ts [32][136] @10240
  unsigned short* Gs = (unsigned short*)(arena);
  unsigned short* Ts = (unsigned short*)(arena + 10240);
#pragma unroll
  for (int i2 = 0; i2 < 2; i2++) {
#pragma unroll
    for (int j = 0; j < 2; j++) {      // h0 -> dscale*h0
      int f = f0 + j * 16 + lr;
#pragma unroll
      for (int r = 0; r < 4; r++) {
        int rloc = arow0 + i2 * 16 + qu * 4 + r;
        int n = rloc & 63;
        Gs[rloc * 40 + j * 16 + lr] = f2bf(dscale[n * 256 + f] * acc[i2][j][r]);
      }
    }
#pragma unroll
    for (int j = 2; j < 4; j++) {      // h1 -> Ts[fl][rloc]
      int fl = (j - 2) * 16 + lr;
      int rb = arow0 + i2 * 16 + qu * 4;
      u16x4 pk;
      pk[0] = f2bf(acc[i2][j][0]); pk[1] = f2bf(acc[i2][j][1]);
      pk[2] = f2bf(acc[i2][j][2]); pk[3] = f2bf(acc[i2][j][3]);
      *(u16x4*)(Ts + fl * 136 + rb) = pk;
    }
  }
  __syncthreads();

  {   // g0: 2 threads/row, 32B each
    int row = tid >> 1, half = tid & 1;
    const unsigned short* sp = Gs + row * 40 + half * 16;
    unsigned short* dp = g0g + (R0 + row) * 256 + f0 + half * 16;
    *(u16x8*)dp = *(const u16x8*)sp;
    *(u16x8*)(dp + 8) = *(const u16x8*)(sp + 8);
  }
  {   // h1t: 8 threads/f, 32B each
    int f = tid >> 3, seg = tid & 7;
    const unsigned short* sp = Ts + f * 136 + seg * 16;
    unsigned short* dp = h1t + (long)(f0 + f) * 131072 + R0 + seg * 16;
    *(u16x8*)dp = *(const u16x8*)sp;
    *(u16x8*)(dp + 8) = *(const u16x8*)(sp + 8);
  }
}

// ---------------------------------------------------------------- k_eout
// grid 2048, block 256 (4 waves). Block = 16 batches x 16 f, all 64 n.
// Hs = h1t slice [16 f][16 b][64 m] (32KB, gl16 once, XOR-swizzled);
// off[f] 8KB dbuf (gl16, 1 barrier per f-step). Per f: C[n,b] via 2 MFMAs
// per wave (wave owns n in [wid*16, wid*16+16), b = lr). f-results
// accumulate in registers (packed bf16); epilogue = g0 + eins + bias.
__global__ __launch_bounds__(256, 4) void k_eout(const float* __restrict__ bias,
                                                 const char* __restrict__ ws_b,
                                                 float* __restrict__ out) {
  const char* off_b = ws_b + OFF_OFF;
  const char* h1t_b = ws_b + OFF_H1T;
  const unsigned short* g0g = (const unsigned short*)(ws_b + OFF_G0);

  __shared__ __align__(16) char arena[49152];   // Hs @0 (32KB), Obuf @32K (2x8KB)

  const int tid = threadIdx.x;
  const int wid = tid >> 6, lane = tid & 63;
  const int lr = lane & 15, qu = lane >> 4;

  const int wg = blockIdx.x;
  const int xcd = wg & 7, u = wg >> 3;           // u 0..255
  const int bg = xcd * 16 + (u >> 4);            // 0..127 (16-batch groups)
  const int fg = u & 15;                         // f-group cycles fast (L2)
  const long B0 = (long)bg * 16;
  const int f0 = fg * 16;
  const int nw = wid * 16;

  // ---- stage Hs: 16 f x 2KB contiguous, pre-swizzled source (rule 21)
  {
    const int bb = (tid & 127) >> 3;             // b row within f-slice
    const int sw = ((tid & 7) ^ (bb & 7)) << 4;  // permuted 16B slot in 128B row
#pragma unroll
    for (int i = 0; i < 8; i++) {
      int f = f0 + i * 2 + (tid >> 7);
      gl16(h1t_b + (long)f * 262144 + bg * 2048 + bb * 128 + sw,
           arena + i * 4096 + tid * 16);
    }
  }
  // ---- stage off[f0] -> Obuf0 (8KB, 2 calls)
  const int onr = tid >> 3;                      // n row (within 32-group)
  const int osw = ((tid & 7) ^ (onr & 7)) << 4;
  {
#pragma unroll
    for (int j = 0; j < 2; j++)
      gl16(off_b + (long)f0 * 8192 + j * 4096 + onr * 128 + osw,
           arena + 32768 + j * 4096 + tid * 16);
  }

  unsigned int eb[4][8];   // [j][f-pair] packed bf16 eins accumulators
  f32x4 ep;

#pragma unroll
  for (int fi = 0; fi < 16; fi++) {
    __syncthreads();       // vmcnt drained: Obuf[fi&1] (and Hs at fi=0) ready
    if (fi < 15) {         // stage next off tile into the idle buffer
#pragma unroll
      for (int j = 0; j < 2; j++)
        gl16(off_b + (long)(f0 + fi + 1) * 8192 + j * 4096 + onr * 128 + osw,
             arena + 32768 + ((fi + 1) & 1) * 8192 + j * 4096 + tid * 16);
    }
    const char* ob = arena + 32768 + (fi & 1) * 8192;
    const char* hb = arena + fi * 2048;
    f32x4 e = {};
#pragma unroll
    for (int kk = 0; kk < 2; kk++) {
      int n = nw + lr;
      fragA a = *(const fragA*)(ob + n * 128 + (((kk * 4 + qu) ^ (n & 7)) << 4));
      fragA b = *(const fragA*)(hb + lr * 128 + (((kk * 4 + qu) ^ (lr & 7)) << 4));
      e = mfma16(a, b, e);
    }
    if (fi & 1) {
#pragma unroll
      for (int j = 0; j < 4; j++) eb[j][fi >> 1] = packbf(ep[j], e[j]);
    } else {
      ep = e;
    }
  }

  // ---- epilogue: out = g0 + eins + bias (per lane: 4 rows x 16 f)
  float4 bv[4];
#pragma unroll
  for (int k = 0; k < 4; k++) bv[k] = ((const float4*)(bias + f0))[k];

#pragma unroll
  for (int j = 0; j < 4; j++) {
    long R = (B0 + lr) * 64 + nw + qu * 4 + j;
    const unsigned short* gp = g0g + R * 256 + f0;
    u16x8 gv0 = ((const u16x8*)gp)[0];
    u16x8 gv1 = ((const u16x8*)gp)[1];
    float4* op = (float4*)(out + R * 256 + f0);
#pragma unroll
    for (int k = 0; k < 4; k++) {
      unsigned int p0 = eb[j][k * 2], p1 = eb[j][k * 2 + 1];
      float g0e = bf2f(k < 2 ? gv0[k * 4 + 0] : gv1[(k - 2) * 4 + 0]);
      float g1e = bf2f(k < 2 ? gv0[k * 4 + 1] : gv1[(k - 2) * 4 + 1]);
      float g2e = bf2f(k < 2 ? gv0[k * 4 + 2] : gv1[(k - 2) * 4 + 2]);
      float g3e = bf2f(k < 2 ? gv0[k * 4 + 3] : gv1[(k - 2) * 4 + 3]);
      float4 ov;
      ov.x = g0e + bf2f((unsigned short)(p0 & 0xffff)) + bv[k].x;
      ov.y = g1e + bf2f((unsigned short)(p0 >> 16)) + bv[k].y;
      ov.z = g2e + bf2f((unsigned short)(p1 & 0xffff)) + bv[k].z;
      ov.w = g3e + bf2f((unsigned short)(p1 >> 16)) + bv[k].w;
      op[k] = ov;
    }
  }
}

// ---------------------------------------------------------------- launch
extern "C" void kernel_launch(void* const* d_in, const int* in_sizes, int n_in,
                              void* d_out, int out_size, void* d_ws, size_t ws_size,
                              hipStream_t stream) {
  const float* x    = (const float*)d_in[0];
  const float* W    = (const float*)d_in[1];
  const float* e    = (const float*)d_in[2];
  const float* bias = (const float*)d_in[3];
  const unsigned char* mask = (const unsigned char*)d_in[4];
  float* out = (float*)d_out;
  char* ws = (char*)d_ws;
  if (ws_size < (size_t)WS_NEED) return;

  k_pre<<<6176, 256, 0, stream>>>(x, e, W, mask, ws);
  k_gemm<<<8192, 256, 0, stream>>>(ws);
  k_eout<<<2048, 256, 0, stream>>>(bias, ws, out);
}